// Round 6
// baseline (295.615 us; speedup 1.0000x reference)
//
#include <hip/hip_runtime.h>

typedef unsigned short u16;
typedef _Float16 f16x8 __attribute__((ext_vector_type(8)));
typedef _Float16 f16x2 __attribute__((ext_vector_type(2)));
typedef float f32x4 __attribute__((ext_vector_type(4)));

// ---------- helpers ----------
__device__ __forceinline__ u16 f2h(float f){
  _Float16 h = (_Float16)f;                 // RNE f32->f16
  return __builtin_bit_cast(u16, h);
}

__device__ __forceinline__ void load_lds16(const void* g, void* l){
  __builtin_amdgcn_global_load_lds((const __attribute__((address_space(1))) void*)g,
                                   (__attribute__((address_space(3))) void*)l,
                                   16, 0, 0);
}

// ---------- bev NCHW f32 -> padded NHWC f16 (8,202,202,64), interior only ----------
__global__ __launch_bounds__(256) void kv6_transpose(const float* __restrict__ bev,
                                                     u16* __restrict__ bevT)
{
  __shared__ float t[64][65];
  const int tid = threadIdx.x;
  const int bid = blockIdx.x;
  const int wc = bid & 3;
  const int h  = (bid >> 2) % 200;
  const int b  = bid / 800;
  const int w0 = wc << 6;

  const int wl = (tid & 15) << 2;
  const int cb = tid >> 4;
  if (w0 + wl < 200){
    #pragma unroll
    for (int r = 0; r < 4; ++r){
      const int c = cb + (r << 4);
      const float4 v = *(const float4*)&bev[(((size_t)b*64 + c)*200 + h)*200 + (w0 + wl)];
      t[c][wl] = v.x; t[c][wl+1] = v.y; t[c][wl+2] = v.z; t[c][wl+3] = v.w;
    }
  }
  __syncthreads();
  const int c0 = (tid & 7) << 3;
  #pragma unroll
  for (int j = 0; j < 2; ++j){
    const int wl2 = (tid >> 3) + (j << 5);
    if (w0 + wl2 < 200){
      unsigned r0 = (unsigned)f2h(t[c0+0][wl2]) | ((unsigned)f2h(t[c0+1][wl2]) << 16);
      unsigned r1 = (unsigned)f2h(t[c0+2][wl2]) | ((unsigned)f2h(t[c0+3][wl2]) << 16);
      unsigned r2 = (unsigned)f2h(t[c0+4][wl2]) | ((unsigned)f2h(t[c0+5][wl2]) << 16);
      unsigned r3 = (unsigned)f2h(t[c0+6][wl2]) | ((unsigned)f2h(t[c0+7][wl2]) << 16);
      uint4 o = {r0, r1, r2, r3};
      *(uint4*)&bevT[(((size_t)b*202 + h + 1)*202 + (w0 + wl2 + 1))*64 + c0] = o;
    }
  }
}

// ---------- weight prep: conv_w -> Wr[t9][d][c] f16 ; out_w -> owb[d][c] f16 ----------
__global__ __launch_bounds__(256) void kv6_prep(const float* __restrict__ conv_w,
                                                const float* __restrict__ out_w,
                                                u16* __restrict__ Wr,
                                                u16* __restrict__ owb)
{
  const int i = blockIdx.x * 256 + threadIdx.x;
  if (i < 9*256*64){
    const int t9 = i / (256*64);
    const int rem = i - t9*(256*64);
    const int d = rem >> 6, c = rem & 63;
    Wr[i] = f2h(conv_w[(size_t)(d*64 + c)*9 + t9]);
  } else {
    const int j = i - 9*256*64;
    if (j < 65536) owb[j] = f2h(out_w[j]);
  }
}

// ---------- attention weights: softmax(queries @ attn_w^T + attn_b), f32 ----------
__global__ __launch_bounds__(256) void kv6_attw(const float* __restrict__ q,
                                                const float* __restrict__ aw,
                                                const float* __restrict__ ab,
                                                float* __restrict__ attw)
{
  const int lane = threadIdx.x & 63;
  const int bq = blockIdx.x * 4 + (threadIdx.x >> 6);
  const float4 qv = *(const float4*)&q[(size_t)bq*256 + (lane << 2)];
  float lg[8];
  #pragma unroll
  for (int p = 0; p < 8; ++p){
    const float4 wv = *(const float4*)&aw[p*256 + (lane << 2)];
    float d = qv.x*wv.x + qv.y*wv.y + qv.z*wv.z + qv.w*wv.w;
    #pragma unroll
    for (int off = 32; off > 0; off >>= 1) d += __shfl_xor(d, off);
    lg[p] = d + ab[p];
  }
  float mx = lg[0];
  #pragma unroll
  for (int p = 1; p < 8; ++p) mx = fmaxf(mx, lg[p]);
  float sum = 0.f;
  #pragma unroll
  for (int p = 0; p < 8; ++p){ lg[p] = expf(lg[p] - mx); sum += lg[p]; }
  const float inv = 1.f / sum;
  if (lane == 0){
    float4 o0 = {lg[0]*inv, lg[1]*inv, lg[2]*inv, lg[3]*inv};
    float4 o1 = {lg[4]*inv, lg[5]*inv, lg[6]*inv, lg[7]*inv};
    *(float4*)&attw[(size_t)bq*8]     = o0;
    *(float4*)&attw[(size_t)bq*8 + 4] = o1;
  }
}

// ---------- conv3x3 + bias + relu, implicit GEMM ----------
// v6: stage the 9-tap UNION strip once (<=68.6KB, 17x16B/thread linear blit),
// ONE barrier, then 9 taps of pure ds_read+MFMA (no intermediate barriers).
// B (weights) streamed global->regs per tap (L2-broadcast). Per-batch M-tiling
// (313 tiles/batch, last is 64-row half tile). XCD-bijective grid: batch=bid&7,
// n=(bid>>3)&1, slot=bid>>4 -> N-pair shares XCD, adjacent slots share strip data.
__global__ __launch_bounds__(256) void kv6_conv(const u16* __restrict__ bevT,
                                                const u16* __restrict__ Wr,
                                                const float* __restrict__ conv_b,
                                                u16* __restrict__ value)
{
  __shared__ __align__(16) u16 lds[34816];   // 69,632 B strip; reused as [128][128] epilogue
  const int tid  = threadIdx.x;
  const int bid  = blockIdx.x;
  const int b    = bid & 7;                  // batch == XCD
  const int n0   = ((bid >> 3) & 1) << 7;
  const int slot = bid >> 4;                 // 0..312 tile within batch
  const int rows_valid = (slot == 312) ? 64 : 128;

  const int pix0 = slot << 7;                // within-batch first pixel
  const int h0   = pix0 / 200;
  const int w0   = pix0 - h0 * 200;
  const size_t strip_base = ((size_t)(b*202 + h0)*202 + w0) * 64;  // tap(0,0) of row 0

  // stage strip: linear 16B blit (global_load_lds requires linear dest)
  #pragma unroll
  for (int i = 0; i < 17; ++i){
    const int idx = (i << 8) + tid;
    load_lds16(bevT + strip_base + ((size_t)idx << 3), lds + (idx << 3));
  }

  const int lane = tid & 63;
  const int wv   = tid >> 6;
  const int wm   = (wv >> 1) << 6;
  const int wn   = (wv & 1) << 6;
  const int ko   = (lane >> 4) << 3;         // k-subchunk 0/8/16/24

  // per-lane row offsets: A rows in strip (u16), B rows in Wr (u16)
  int rowoffA[4], rowBidx[4];
  #pragma unroll
  for (int f = 0; f < 4; ++f){
    const int r = wm + (f << 4) + (lane & 15);
    rowoffA[f] = (r << 6) + ((w0 + r >= 200) ? 128 : 0);   // +2 pads on h-row crossing
    rowBidx[f] = (n0 + wn + (f << 4) + (lane & 15)) << 6;
  }

  const f32x4 z = {0.f, 0.f, 0.f, 0.f};
  f32x4 acc[4][4];
  #pragma unroll
  for (int mf = 0; mf < 4; ++mf)
    #pragma unroll
    for (int nf = 0; nf < 4; ++nf)
      acc[mf][nf] = z;

  __syncthreads();                           // strip ready (vmcnt drain + barrier)

  #pragma unroll 1
  for (int t9 = 0; t9 < 9; ++t9){
    const int ky = (t9 * 11) >> 5;           // t9/3 for 0..8
    const int kx = t9 - ky * 3;
    const int tapoff = (ky * 202 + kx) << 6;
    const u16* wsrc = Wr + t9 * 16384;

    f16x8 bf[2][4], af[2][4];
    #pragma unroll
    for (int kh = 0; kh < 2; ++kh)
      #pragma unroll
      for (int f = 0; f < 4; ++f)
        bf[kh][f] = *(const f16x8*)&wsrc[rowBidx[f] + (kh << 5) + ko];
    #pragma unroll
    for (int kh = 0; kh < 2; ++kh)
      #pragma unroll
      for (int f = 0; f < 4; ++f)
        af[kh][f] = *(const f16x8*)&lds[rowoffA[f] + tapoff + (kh << 5) + ko];

    #pragma unroll
    for (int kh = 0; kh < 2; ++kh)
      #pragma unroll
      for (int mf = 0; mf < 4; ++mf)
        #pragma unroll
        for (int nf = 0; nf < 4; ++nf)
          acc[mf][nf] = __builtin_amdgcn_mfma_f32_16x16x32_f16(af[kh][mf], bf[kh][nf], acc[mf][nf], 0, 0, 0);
  }

  __syncthreads();                           // all waves done reading strip

  // epilogue: bias + relu -> f16 -> LDS [128][128] -> coalesced 16B stores
  const int m0 = b * 40000 + pix0;
  #pragma unroll
  for (int nf = 0; nf < 4; ++nf){
    const int col = wn + (nf << 4) + (lane & 15);
    const float bias = conv_b[n0 + col];
    #pragma unroll
    for (int mf = 0; mf < 4; ++mf)
      #pragma unroll
      for (int rr = 0; rr < 4; ++rr){
        const int row = wm + (mf << 4) + ((lane >> 4) << 2) + rr;
        lds[row*128 + col] = f2h(fmaxf(acc[mf][nf][rr] + bias, 0.f));
      }
  }
  __syncthreads();
  #pragma unroll
  for (int it = 0; it < 8; ++it){
    const int idx = (it << 8) + tid;
    const int row = idx >> 4;
    if (row < rows_valid){
      const int ce = (idx & 15) << 3;
      const f32x4 v = *(const f32x4*)&lds[row*128 + ce];
      *(f32x4*)&value[(size_t)(m0 + row)*256 + n0 + ce] = v;
    }
  }
}

// ---------- bilinear sample + attention-weighted sum; s stored f16 ----------
__global__ __launch_bounds__(256) void kv6_sample(const float* __restrict__ traj,
                                                  const float* __restrict__ attw,
                                                  const u16* __restrict__ value,
                                                  u16* __restrict__ sbh)
{
  __shared__ int   pixs[2][32];
  __shared__ float wgts[2][32];
  const int tid  = threadIdx.x;
  const int half = tid >> 7;
  const int t    = tid & 127;
  const int q    = (blockIdx.x << 1) + half;

  if (t < 8){
    const int p = t;
    const float ty = traj[((size_t)q*8 + p)*2 + 0];   // -> gy (grid = norm[..., ::-1])
    const float tx = traj[((size_t)q*8 + p)*2 + 1];   // -> gx
    float aw = attw[q*8 + p];
    const float gxn = tx / 30.f;
    const float gyn = ty / 30.f;
    if (!(gxn >= -1.f && gxn <= 1.f && gyn >= -1.f && gyn <= 1.f)) aw = 0.f;
    const float gx = (gxn + 1.f) * 0.5f * 199.f;
    const float gy = (gyn + 1.f) * 0.5f * 199.f;
    int x0 = (int)gx; x0 = min(max(x0, 0), 198);      // trunc-cast then clip, like reference
    int y0 = (int)gy; y0 = min(max(y0, 0), 198);
    const float wx = fminf(fmaxf(gx - (float)x0, 0.f), 1.f);
    const float wy = fminf(fmaxf(gy - (float)y0, 0.f), 1.f);
    const int base = y0*200 + x0;
    pixs[half][p*4+0] = base;       wgts[half][p*4+0] = aw*(1.f-wx)*(1.f-wy);
    pixs[half][p*4+1] = base+1;     wgts[half][p*4+1] = aw*wx*(1.f-wy);
    pixs[half][p*4+2] = base+200;   wgts[half][p*4+2] = aw*(1.f-wx)*wy;
    pixs[half][p*4+3] = base+201;   wgts[half][p*4+3] = aw*wx*wy;
  }
  __syncthreads();
  const size_t vbase = (size_t)(q >> 11) * 40000;     // b * H*W
  float a0 = 0.f, a1 = 0.f;
  #pragma unroll
  for (int i = 0; i < 32; ++i){
    const float w = wgts[half][i];
    const f16x2 pv = *(const f16x2*)&value[((vbase + pixs[half][i]) << 8) + (t << 1)];
    a0 = fmaf(w, (float)pv.x, a0);
    a1 = fmaf(w, (float)pv.y, a1);
  }
  const unsigned o = (unsigned)f2h(a0) | ((unsigned)f2h(a1) << 16);
  *(unsigned*)&sbh[((size_t)q << 8) + (t << 1)] = o;
}

// ---------- out = s @ out_w^T + out_b + queries : M=16384, N=256, K=256 (f16 MFMA) ----------
__global__ __launch_bounds__(256) void kv6_outgemm(const u16* __restrict__ sbh,
                                                   const u16* __restrict__ owb,
                                                   const float* __restrict__ out_b,
                                                   const float* __restrict__ queries,
                                                   float* __restrict__ outp)
{
  __shared__ __align__(16) u16 lds[16384];
  const int tid  = threadIdx.x;
  const int bid  = blockIdx.x;
  const int n0   = (bid & 1) << 7;
  const int m0   = (bid >> 1) << 7;
  const int lane = tid & 63;
  const int wv   = tid >> 6;
  const int wm   = (wv >> 1) << 6;
  const int wn   = (wv & 1) << 6;
  const int c0   = (tid & 7) << 3;

  int baseA[4], baseB[4];
  #pragma unroll
  for (int i = 0; i < 4; ++i){
    baseA[i] = (m0 + (i << 5) + (tid >> 3))*256 + c0;
    baseB[i] = (n0 + (i << 5) + (tid >> 3))*256 + c0;
  }
  const f32x4 z = {0.f, 0.f, 0.f, 0.f};
  f32x4 acc[4][4];
  #pragma unroll
  for (int mf = 0; mf < 4; ++mf)
    #pragma unroll
    for (int nf = 0; nf < 4; ++nf)
      acc[mf][nf] = z;

  for (int kk = 0; kk < 4; ++kk){
    #pragma unroll
    for (int i = 0; i < 4; ++i){
      load_lds16(sbh + baseA[i] + (kk << 6), lds + (i << 11) + (wv << 9));
      load_lds16(owb + baseB[i] + (kk << 6), lds + 8192 + (i << 11) + (wv << 9));
    }
    __syncthreads();

    f16x8 a_frag[2][4], b_frag[2][4];
    #pragma unroll
    for (int kh = 0; kh < 2; ++kh){
      const int kq = (kh << 5) + ((lane >> 4) << 3);
      #pragma unroll
      for (int f = 0; f < 4; ++f){
        a_frag[kh][f] = *(const f16x8*)&lds[(wm + (f << 4) + (lane & 15))*64 + kq];
        b_frag[kh][f] = *(const f16x8*)&lds[8192 + (wn + (f << 4) + (lane & 15))*64 + kq];
      }
    }
    #pragma unroll
    for (int kh = 0; kh < 2; ++kh)
      #pragma unroll
      for (int mf = 0; mf < 4; ++mf)
        #pragma unroll
        for (int nf = 0; nf < 4; ++nf)
          acc[mf][nf] = __builtin_amdgcn_mfma_f32_16x16x32_f16(a_frag[kh][mf], b_frag[kh][nf], acc[mf][nf], 0, 0, 0);
    __syncthreads();
  }

  #pragma unroll
  for (int nf = 0; nf < 4; ++nf){
    const int col = wn + (nf << 4) + (lane & 15);
    const float ob = out_b[n0 + col];
    #pragma unroll
    for (int mf = 0; mf < 4; ++mf)
      #pragma unroll
      for (int rr = 0; rr < 4; ++rr){
        const int row = wm + (mf << 4) + ((lane >> 4) << 2) + rr;
        const size_t off = (size_t)(m0 + row)*256 + n0 + col;
        outp[off] = acc[mf][nf][rr] + ob + queries[off];
      }
  }
}

// ---------- launch ----------
extern "C" void kernel_launch(void* const* d_in, const int* in_sizes, int n_in,
                              void* d_out, int out_size, void* d_ws, size_t ws_size,
                              hipStream_t stream)
{
  const float* queries = (const float*)d_in[0];
  const float* traj    = (const float*)d_in[1];
  const float* bev     = (const float*)d_in[2];
  const float* attn_w  = (const float*)d_in[3];
  const float* attn_b  = (const float*)d_in[4];
  const float* out_w   = (const float*)d_in[5];
  const float* out_b   = (const float*)d_in[6];
  const float* conv_w  = (const float*)d_in[7];
  const float* conv_b  = (const float*)d_in[8];
  float* outp = (float*)d_out;
  char* ws = (char*)d_ws;

  // workspace layout (bytes); bevT = 8*202*202*64*2 = 41,783,296 (exact)
  u16*   bevT  = (u16*)  (ws + 0);            // 41,783,296
  u16*   value = (u16*)  (ws + 41783296);     // 320000*256*2 = 163,840,000
  u16*   Wr    = (u16*)  (ws + 205623296);    // 9*256*64*2   = 294,912
  u16*   owb   = (u16*)  (ws + 205918208);    // 256*256*2    = 131,072
  float* attw  = (float*)(ws + 206049280);    // 16384*8*4    = 524,288
  u16*   sbh   = (u16*)  (ws + 206573568);    // 16384*256*2  = 8,388,608  (end 214,962,176)

  hipMemsetAsync(bevT, 0, 41783296, stream);                       // zero halo (full array)
  kv6_transpose<<<6400, 256, 0, stream>>>(bev, bevT);
  kv6_prep     <<<832,  256, 0, stream>>>(conv_w, out_w, Wr, owb);
  kv6_attw     <<<4096, 256, 0, stream>>>(queries, attn_w, attn_b, attw);
  kv6_conv     <<<5008, 256, 0, stream>>>(bevT, Wr, conv_b, value);
  kv6_sample   <<<8192, 256, 0, stream>>>(traj, attw, value, sbh);
  kv6_outgemm  <<<256,  256, 0, stream>>>(sbh, owb, out_b, queries, outp);
}

// Round 7
// 285.877 us; speedup vs baseline: 1.0341x; 1.0341x over previous
//
#include <hip/hip_runtime.h>

typedef unsigned short u16;
typedef _Float16 f16x8 __attribute__((ext_vector_type(8)));
typedef _Float16 f16x2 __attribute__((ext_vector_type(2)));
typedef float f32x4 __attribute__((ext_vector_type(4)));

// ---------- helpers ----------
__device__ __forceinline__ u16 f2h(float f){
  _Float16 h = (_Float16)f;                 // RNE f32->f16
  return __builtin_bit_cast(u16, h);
}

__device__ __forceinline__ void load_lds16(const void* g, void* l){
  __builtin_amdgcn_global_load_lds((const __attribute__((address_space(1))) void*)g,
                                   (__attribute__((address_space(3))) void*)l,
                                   16, 0, 0);
}

// ---------- bev NCHW f32 -> padded NHWC f16 (8,202,202,64), interior only ----------
__global__ __launch_bounds__(256) void kv7_transpose(const float* __restrict__ bev,
                                                     u16* __restrict__ bevT)
{
  __shared__ float t[64][65];
  const int tid = threadIdx.x;
  const int bid = blockIdx.x;
  const int wc = bid & 3;
  const int h  = (bid >> 2) % 200;
  const int b  = bid / 800;
  const int w0 = wc << 6;

  const int wl = (tid & 15) << 2;
  const int cb = tid >> 4;
  if (w0 + wl < 200){
    #pragma unroll
    for (int r = 0; r < 4; ++r){
      const int c = cb + (r << 4);
      const float4 v = *(const float4*)&bev[(((size_t)b*64 + c)*200 + h)*200 + (w0 + wl)];
      t[c][wl] = v.x; t[c][wl+1] = v.y; t[c][wl+2] = v.z; t[c][wl+3] = v.w;
    }
  }
  __syncthreads();
  const int c0 = (tid & 7) << 3;
  #pragma unroll
  for (int j = 0; j < 2; ++j){
    const int wl2 = (tid >> 3) + (j << 5);
    if (w0 + wl2 < 200){
      unsigned r0 = (unsigned)f2h(t[c0+0][wl2]) | ((unsigned)f2h(t[c0+1][wl2]) << 16);
      unsigned r1 = (unsigned)f2h(t[c0+2][wl2]) | ((unsigned)f2h(t[c0+3][wl2]) << 16);
      unsigned r2 = (unsigned)f2h(t[c0+4][wl2]) | ((unsigned)f2h(t[c0+5][wl2]) << 16);
      unsigned r3 = (unsigned)f2h(t[c0+6][wl2]) | ((unsigned)f2h(t[c0+7][wl2]) << 16);
      uint4 o = {r0, r1, r2, r3};
      *(uint4*)&bevT[(((size_t)b*202 + h + 1)*202 + (w0 + wl2 + 1))*64 + c0] = o;
    }
  }
}

// ---------- weight prep: conv_w -> Wr[t9][d][c] f16 ; out_w -> owb[d][c] f16 ----------
__global__ __launch_bounds__(256) void kv7_prep(const float* __restrict__ conv_w,
                                                const float* __restrict__ out_w,
                                                u16* __restrict__ Wr,
                                                u16* __restrict__ owb)
{
  const int i = blockIdx.x * 256 + threadIdx.x;
  if (i < 9*256*64){
    const int t9 = i / (256*64);
    const int rem = i - t9*(256*64);
    const int d = rem >> 6, c = rem & 63;
    Wr[i] = f2h(conv_w[(size_t)(d*64 + c)*9 + t9]);
  } else {
    const int j = i - 9*256*64;
    if (j < 65536) owb[j] = f2h(out_w[j]);
  }
}

// ---------- attention weights: softmax(queries @ attn_w^T + attn_b), f32 ----------
__global__ __launch_bounds__(256) void kv7_attw(const float* __restrict__ q,
                                                const float* __restrict__ aw,
                                                const float* __restrict__ ab,
                                                float* __restrict__ attw)
{
  const int lane = threadIdx.x & 63;
  const int bq = blockIdx.x * 4 + (threadIdx.x >> 6);
  const float4 qv = *(const float4*)&q[(size_t)bq*256 + (lane << 2)];
  float lg[8];
  #pragma unroll
  for (int p = 0; p < 8; ++p){
    const float4 wv = *(const float4*)&aw[p*256 + (lane << 2)];
    float d = qv.x*wv.x + qv.y*wv.y + qv.z*wv.z + qv.w*wv.w;
    #pragma unroll
    for (int off = 32; off > 0; off >>= 1) d += __shfl_xor(d, off);
    lg[p] = d + ab[p];
  }
  float mx = lg[0];
  #pragma unroll
  for (int p = 1; p < 8; ++p) mx = fmaxf(mx, lg[p]);
  float sum = 0.f;
  #pragma unroll
  for (int p = 0; p < 8; ++p){ lg[p] = expf(lg[p] - mx); sum += lg[p]; }
  const float inv = 1.f / sum;
  if (lane == 0){
    float4 o0 = {lg[0]*inv, lg[1]*inv, lg[2]*inv, lg[3]*inv};
    float4 o1 = {lg[4]*inv, lg[5]*inv, lg[6]*inv, lg[7]*inv};
    *(float4*)&attw[(size_t)bq*8]     = o0;
    *(float4*)&attw[(size_t)bq*8 + 4] = o1;
  }
}

// ---------- conv helpers (v7) ----------
__device__ __forceinline__ void loadB(const u16* __restrict__ Wr, int t9,
                                      const int* rowBidx, int ko, f16x8 (&bf)[2][4])
{
  const u16* ws = Wr + t9*16384;
  #pragma unroll
  for (int kh = 0; kh < 2; ++kh)
    #pragma unroll
    for (int f = 0; f < 4; ++f)
      bf[kh][f] = *(const f16x8*)&ws[rowBidx[f] + (kh << 5) + ko];
}

template<int T9>
__device__ __forceinline__ void tapMFMA(const u16* lds, const int* rowpix, int klo,
                                        const f16x8 (&bf)[2][4], f32x4 (&acc)[4][4])
{
  constexpr int ky = T9 / 3, kx = T9 % 3;
  constexpr int tappix = ky * 202 + kx;
  f16x8 af[2][4];
  #pragma unroll
  for (int f = 0; f < 4; ++f){
    const int p  = rowpix[f] + tappix;
    const int sw = p & 7;
    af[0][f] = *(const f16x8*)&lds[(p << 6) + (((klo    ) ^ sw) << 3)];
    af[1][f] = *(const f16x8*)&lds[(p << 6) + (((klo + 4) ^ sw) << 3)];
  }
  #pragma unroll
  for (int kh = 0; kh < 2; ++kh)
    #pragma unroll
    for (int mf = 0; mf < 4; ++mf)
      #pragma unroll
      for (int nf = 0; nf < 4; ++nf)
        acc[mf][nf] = __builtin_amdgcn_mfma_f32_16x16x32_f16(af[kh][mf], bf[kh][nf], acc[mf][nf], 0, 0, 0);
}

// ---------- conv3x3 + bias + relu, implicit GEMM ----------
// v7 = v6 strip structure (stage 9-tap union once, 2 barriers total) +
// (a) T2 XOR swizzle on strip: linear LDS dest, inverse-swizzled GLOBAL source
//     (chunk c of pixel p holds global chunk c^(p&7)), reads apply same XOR ->
//     bank-group = chunk^(p&7) spreads 16-lane quarter over all 8 groups;
// (b) B weights software-pipelined global->reg one tap ahead (named double
//     buffer, fully unrolled ladder -> counted vmcnt waits, no runtime idx).
__global__ __launch_bounds__(256) void kv7_conv(const u16* __restrict__ bevT,
                                                const u16* __restrict__ Wr,
                                                const float* __restrict__ conv_b,
                                                u16* __restrict__ value)
{
  __shared__ __align__(16) u16 lds[34816];   // 69,632 B strip; reused as [128][128] epilogue
  const int tid  = threadIdx.x;
  const int bid  = blockIdx.x;
  const int b    = bid & 7;                  // batch == XCD
  const int n0   = ((bid >> 3) & 1) << 7;
  const int slot = bid >> 4;                 // 0..312 tile within batch
  const int rows_valid = (slot == 312) ? 64 : 128;

  const int pix0 = slot << 7;
  const int h0   = pix0 / 200;
  const int w0   = pix0 - h0 * 200;
  const size_t strip_base = ((size_t)(b*202 + h0)*202 + w0) * 64;  // tap(0,0) of row 0

  const int lane = tid & 63;
  const int wv   = tid >> 6;

  // stage strip: linear LDS dest (wave-uniform base; HW adds lane*16B),
  // global source pre-swizzled within each 128B pixel row: chunk ^= (p&7)
  #pragma unroll
  for (int i = 0; i < 17; ++i){
    const int idx = (i << 8) + tid;                       // chunk index = p*8 + c
    const int src = ((idx & ~7) | ((idx & 7) ^ ((idx >> 3) & 7))) << 3;
    load_lds16(bevT + strip_base + src, lds + (i << 11) + (wv << 9));
  }

  const int wm   = (wv >> 1) << 6;
  const int wn   = (wv & 1) << 6;
  const int klo  = lane >> 4;                // k-chunk 0..3 (kh adds 4)

  int rowpix[4], rowBidx[4];
  #pragma unroll
  for (int f = 0; f < 4; ++f){
    const int r = wm + (f << 4) + (lane & 15);
    rowpix[f]  = r + ((w0 + r >= 200) ? 2 : 0);           // +2 halo pixels on h-row crossing
    rowBidx[f] = (n0 + wn + (f << 4) + (lane & 15)) << 6;
  }

  const f32x4 z = {0.f, 0.f, 0.f, 0.f};
  f32x4 acc[4][4];
  #pragma unroll
  for (int mf = 0; mf < 4; ++mf)
    #pragma unroll
    for (int nf = 0; nf < 4; ++nf)
      acc[mf][nf] = z;

  f16x8 b0[2][4], b1[2][4];
  loadB(Wr, 0, rowBidx, klo << 3, b0);
  __syncthreads();                           // strip + b0 ready (vmcnt drain + barrier)

  const int ko = klo << 3;
  loadB(Wr, 1, rowBidx, ko, b1);  tapMFMA<0>(lds, rowpix, klo, b0, acc);
  loadB(Wr, 2, rowBidx, ko, b0);  tapMFMA<1>(lds, rowpix, klo, b1, acc);
  loadB(Wr, 3, rowBidx, ko, b1);  tapMFMA<2>(lds, rowpix, klo, b0, acc);
  loadB(Wr, 4, rowBidx, ko, b0);  tapMFMA<3>(lds, rowpix, klo, b1, acc);
  loadB(Wr, 5, rowBidx, ko, b1);  tapMFMA<4>(lds, rowpix, klo, b0, acc);
  loadB(Wr, 6, rowBidx, ko, b0);  tapMFMA<5>(lds, rowpix, klo, b1, acc);
  loadB(Wr, 7, rowBidx, ko, b1);  tapMFMA<6>(lds, rowpix, klo, b0, acc);
  loadB(Wr, 8, rowBidx, ko, b0);  tapMFMA<7>(lds, rowpix, klo, b1, acc);
                                  tapMFMA<8>(lds, rowpix, klo, b0, acc);

  __syncthreads();                           // all waves done reading strip

  // epilogue: bias + relu -> f16 -> LDS [128][128] -> coalesced 16B stores
  const int m0 = b * 40000 + pix0;
  #pragma unroll
  for (int nf = 0; nf < 4; ++nf){
    const int col = wn + (nf << 4) + (lane & 15);
    const float bias = conv_b[n0 + col];
    #pragma unroll
    for (int mf = 0; mf < 4; ++mf)
      #pragma unroll
      for (int rr = 0; rr < 4; ++rr){
        const int row = wm + (mf << 4) + ((lane >> 4) << 2) + rr;
        lds[row*128 + col] = f2h(fmaxf(acc[mf][nf][rr] + bias, 0.f));
      }
  }
  __syncthreads();
  #pragma unroll
  for (int it = 0; it < 8; ++it){
    const int idx = (it << 8) + tid;
    const int row = idx >> 4;
    if (row < rows_valid){
      const int ce = (idx & 15) << 3;
      const f32x4 v = *(const f32x4*)&lds[row*128 + ce];
      *(f32x4*)&value[(size_t)(m0 + row)*256 + n0 + ce] = v;
    }
  }
}

// ---------- bilinear sample + attention-weighted sum; s stored f16 ----------
__global__ __launch_bounds__(256) void kv7_sample(const float* __restrict__ traj,
                                                  const float* __restrict__ attw,
                                                  const u16* __restrict__ value,
                                                  u16* __restrict__ sbh)
{
  __shared__ int   pixs[2][32];
  __shared__ float wgts[2][32];
  const int tid  = threadIdx.x;
  const int half = tid >> 7;
  const int t    = tid & 127;
  const int q    = (blockIdx.x << 1) + half;

  if (t < 8){
    const int p = t;
    const float ty = traj[((size_t)q*8 + p)*2 + 0];   // -> gy (grid = norm[..., ::-1])
    const float tx = traj[((size_t)q*8 + p)*2 + 1];   // -> gx
    float aw = attw[q*8 + p];
    const float gxn = tx / 30.f;
    const float gyn = ty / 30.f;
    if (!(gxn >= -1.f && gxn <= 1.f && gyn >= -1.f && gyn <= 1.f)) aw = 0.f;
    const float gx = (gxn + 1.f) * 0.5f * 199.f;
    const float gy = (gyn + 1.f) * 0.5f * 199.f;
    int x0 = (int)gx; x0 = min(max(x0, 0), 198);      // trunc-cast then clip, like reference
    int y0 = (int)gy; y0 = min(max(y0, 0), 198);
    const float wx = fminf(fmaxf(gx - (float)x0, 0.f), 1.f);
    const float wy = fminf(fmaxf(gy - (float)y0, 0.f), 1.f);
    const int base = y0*200 + x0;
    pixs[half][p*4+0] = base;       wgts[half][p*4+0] = aw*(1.f-wx)*(1.f-wy);
    pixs[half][p*4+1] = base+1;     wgts[half][p*4+1] = aw*wx*(1.f-wy);
    pixs[half][p*4+2] = base+200;   wgts[half][p*4+2] = aw*(1.f-wx)*wy;
    pixs[half][p*4+3] = base+201;   wgts[half][p*4+3] = aw*wx*wy;
  }
  __syncthreads();
  const size_t vbase = (size_t)(q >> 11) * 40000;     // b * H*W
  float a0 = 0.f, a1 = 0.f;
  #pragma unroll
  for (int i = 0; i < 32; ++i){
    const float w = wgts[half][i];
    const f16x2 pv = *(const f16x2*)&value[((vbase + pixs[half][i]) << 8) + (t << 1)];
    a0 = fmaf(w, (float)pv.x, a0);
    a1 = fmaf(w, (float)pv.y, a1);
  }
  const unsigned o = (unsigned)f2h(a0) | ((unsigned)f2h(a1) << 16);
  *(unsigned*)&sbh[((size_t)q << 8) + (t << 1)] = o;
}

// ---------- out = s @ out_w^T + out_b + queries : M=16384, N=256, K=256 (f16 MFMA) ----------
__global__ __launch_bounds__(256) void kv7_outgemm(const u16* __restrict__ sbh,
                                                   const u16* __restrict__ owb,
                                                   const float* __restrict__ out_b,
                                                   const float* __restrict__ queries,
                                                   float* __restrict__ outp)
{
  __shared__ __align__(16) u16 lds[16384];
  const int tid  = threadIdx.x;
  const int bid  = blockIdx.x;
  const int n0   = (bid & 1) << 7;
  const int m0   = (bid >> 1) << 7;
  const int lane = tid & 63;
  const int wv   = tid >> 6;
  const int wm   = (wv >> 1) << 6;
  const int wn   = (wv & 1) << 6;
  const int c0   = (tid & 7) << 3;

  int baseA[4], baseB[4];
  #pragma unroll
  for (int i = 0; i < 4; ++i){
    baseA[i] = (m0 + (i << 5) + (tid >> 3))*256 + c0;
    baseB[i] = (n0 + (i << 5) + (tid >> 3))*256 + c0;
  }
  const f32x4 z = {0.f, 0.f, 0.f, 0.f};
  f32x4 acc[4][4];
  #pragma unroll
  for (int mf = 0; mf < 4; ++mf)
    #pragma unroll
    for (int nf = 0; nf < 4; ++nf)
      acc[mf][nf] = z;

  for (int kk = 0; kk < 4; ++kk){
    #pragma unroll
    for (int i = 0; i < 4; ++i){
      load_lds16(sbh + baseA[i] + (kk << 6), lds + (i << 11) + (wv << 9));
      load_lds16(owb + baseB[i] + (kk << 6), lds + 8192 + (i << 11) + (wv << 9));
    }
    __syncthreads();

    f16x8 a_frag[2][4], b_frag[2][4];
    #pragma unroll
    for (int kh = 0; kh < 2; ++kh){
      const int kq = (kh << 5) + ((lane >> 4) << 3);
      #pragma unroll
      for (int f = 0; f < 4; ++f){
        a_frag[kh][f] = *(const f16x8*)&lds[(wm + (f << 4) + (lane & 15))*64 + kq];
        b_frag[kh][f] = *(const f16x8*)&lds[8192 + (wn + (f << 4) + (lane & 15))*64 + kq];
      }
    }
    #pragma unroll
    for (int kh = 0; kh < 2; ++kh)
      #pragma unroll
      for (int mf = 0; mf < 4; ++mf)
        #pragma unroll
        for (int nf = 0; nf < 4; ++nf)
          acc[mf][nf] = __builtin_amdgcn_mfma_f32_16x16x32_f16(a_frag[kh][mf], b_frag[kh][nf], acc[mf][nf], 0, 0, 0);
    __syncthreads();
  }

  #pragma unroll
  for (int nf = 0; nf < 4; ++nf){
    const int col = wn + (nf << 4) + (lane & 15);
    const float ob = out_b[n0 + col];
    #pragma unroll
    for (int mf = 0; mf < 4; ++mf)
      #pragma unroll
      for (int rr = 0; rr < 4; ++rr){
        const int row = wm + (mf << 4) + ((lane >> 4) << 2) + rr;
        const size_t off = (size_t)(m0 + row)*256 + n0 + col;
        outp[off] = acc[mf][nf][rr] + ob + queries[off];
      }
  }
}

// ---------- launch ----------
extern "C" void kernel_launch(void* const* d_in, const int* in_sizes, int n_in,
                              void* d_out, int out_size, void* d_ws, size_t ws_size,
                              hipStream_t stream)
{
  const float* queries = (const float*)d_in[0];
  const float* traj    = (const float*)d_in[1];
  const float* bev     = (const float*)d_in[2];
  const float* attn_w  = (const float*)d_in[3];
  const float* attn_b  = (const float*)d_in[4];
  const float* out_w   = (const float*)d_in[5];
  const float* out_b   = (const float*)d_in[6];
  const float* conv_w  = (const float*)d_in[7];
  const float* conv_b  = (const float*)d_in[8];
  float* outp = (float*)d_out;
  char* ws = (char*)d_ws;

  // workspace layout (bytes); bevT = 8*202*202*64*2 = 41,783,296 (exact)
  u16*   bevT  = (u16*)  (ws + 0);            // 41,783,296
  u16*   value = (u16*)  (ws + 41783296);     // 320000*256*2 = 163,840,000
  u16*   Wr    = (u16*)  (ws + 205623296);    // 9*256*64*2   = 294,912
  u16*   owb   = (u16*)  (ws + 205918208);    // 256*256*2    = 131,072
  float* attw  = (float*)(ws + 206049280);    // 16384*8*4    = 524,288
  u16*   sbh   = (u16*)  (ws + 206573568);    // 16384*256*2  = 8,388,608  (end 214,962,176)

  hipMemsetAsync(bevT, 0, 41783296, stream);                       // zero halo (full array)
  kv7_transpose<<<6400, 256, 0, stream>>>(bev, bevT);
  kv7_prep     <<<832,  256, 0, stream>>>(conv_w, out_w, Wr, owb);
  kv7_attw     <<<4096, 256, 0, stream>>>(queries, attn_w, attn_b, attw);
  kv7_conv     <<<5008, 256, 0, stream>>>(bevT, Wr, conv_b, value);
  kv7_sample   <<<8192, 256, 0, stream>>>(traj, attw, value, sbh);
  kv7_outgemm  <<<256,  256, 0, stream>>>(sbh, owb, out_b, queries, outp);
}